// Round 15
// baseline (724.411 us; speedup 1.0000x reference)
//
#include <hip/hip_runtime.h>

typedef __attribute__((ext_vector_type(8))) short s16x8;
typedef __attribute__((ext_vector_type(4))) float f32x4;

__device__ __forceinline__ unsigned short f2bf(float x) {
  unsigned int u = __float_as_uint(x);
  u += 0x7FFFu + ((u >> 16) & 1u);
  return (unsigned short)(u >> 16);
}

__device__ __forceinline__ void gload16(const unsigned short* g, unsigned short* l) {
  __builtin_amdgcn_global_load_lds(
      (const __attribute__((address_space(1))) void*)g,
      (__attribute__((address_space(3))) void*)l, 16, 0, 0);
}

// ---------------- merged prep: weights->bf16, patchify, transposes, zero-fill ----
__global__ __launch_bounds__(256) void prep_kernel(
    const float* __restrict__ conv_w, unsigned short* __restrict__ whi,
    const float* __restrict__ cropped, unsigned short* __restrict__ apat,
    const float* __restrict__ fc1_w, float* __restrict__ fc1T,
    const float* __restrict__ in_w, float* __restrict__ inT,
    const float* __restrict__ out_w, float* __restrict__ outT,
    const float* __restrict__ f1w, float* __restrict__ f1T,
    const float* __restrict__ f2w, float* __restrict__ f2T,
    float* __restrict__ emb_zero) {
  __shared__ float tile[32][33];
  int blk = blockIdx.x;
  int t = threadIdx.x;
  if (blk < 3072) {
    int idx = blk * 256 + t;  // 2048*384
    const float4* s = (const float4*)(conv_w + (size_t)idx * 8);
    float4 v0 = s[0], v1 = s[1];
    unsigned short h8[8] = {f2bf(v0.x), f2bf(v0.y), f2bf(v0.z), f2bf(v0.w),
                            f2bf(v1.x), f2bf(v1.y), f2bf(v1.z), f2bf(v1.w)};
    *(uint4*)&whi[(size_t)idx * 8] = *(const uint4*)h8;
    return;
  }
  if (blk < 5424) {
    int idx = (blk - 3072) * 256 + t;  // 1568*384
    if (idx >= 1568 * 384) return;
    int kseg = idx % 384, row = idx / 384;
    int img = row / 49, pos = row % 49;
    int k = kseg * 8;
    int c = k >> 10, rem = k & 1023, r = rem >> 5, x0 = rem & 31;
    const float* s =
        cropped + ((size_t)(img * 3 + c) * 224 + (pos / 7) * 32 + r) * 224 +
        (pos % 7) * 32 + x0;
    float4 v0 = *(const float4*)(s);
    float4 v1 = *(const float4*)(s + 4);
    unsigned short h8[8] = {f2bf(v0.x), f2bf(v0.y), f2bf(v0.z), f2bf(v0.w),
                            f2bf(v1.x), f2bf(v1.y), f2bf(v1.z), f2bf(v1.w)};
    *(uint4*)&apat[(size_t)row * 3072 + k] = *(const uint4*)h8;
    return;
  }
  if (blk >= 5968) {
    int idx = (blk - 5968) * 256 + t;  // 115080 float4s
    if (idx < 115080) ((float4*)emb_zero)[idx] = (float4){0.f, 0.f, 0.f, 0.f};
    return;
  }
  int id = blk - 5424;  // 544 transpose blocks
  const float* src;
  float* dst;
  int R, C, bx, by;
  if (id < 256) {
    src = fc1_w; dst = fc1T; R = 128; C = 2048; bx = id % 64; by = id / 64;
  } else if (id < 400) {
    id -= 256;
    int z = id / 48, r = id % 48;
    src = in_w + z * 384 * 128; dst = inT + z * 384 * 128;
    R = 384; C = 128; bx = r % 4; by = r / 4;
  } else {
    id -= 400;
    int which = id / 48;  // 0=out, 1=f1, 2=f2
    id -= which * 48;
    int z = id / 16, r = id % 16;
    const float* s3[3] = {out_w, f1w, f2w};
    float* d3[3] = {outT, f1T, f2T};
    src = s3[which] + z * 128 * 128; dst = d3[which] + z * 128 * 128;
    R = 128; C = 128; bx = r % 4; by = r / 4;
  }
  int tx = t & 31, ty = t >> 5;  // 32 x 8
#pragma unroll
  for (int i = 0; i < 32; i += 8) {
    int r = by * 32 + ty + i, c = bx * 32 + tx;
    if (r < R && c < C) tile[ty + i][tx] = src[(size_t)r * C + c];
  }
  __syncthreads();
#pragma unroll
  for (int i = 0; i < 32; i += 8) {
    int r = bx * 32 + ty + i, c = by * 32 + tx;
    if (r < C && c < R) dst[(size_t)r * R + c] = tile[tx][ty + i];
  }
}

// ---------------- window crop/resize -> patchified bf16 [9408][3072] ----------------
__global__ __launch_bounds__(256) void gather_windows(
    const float* __restrict__ img, const int* __restrict__ tl,
    unsigned short* __restrict__ win) {
  int idx = blockIdx.x * 256 + threadIdx.x;  // 9408*384
  if (idx >= 9408 * 384) return;
  int kseg = idx % 384, row = idx / 384;
  int w = row / 49, pos = row % 49;
  int b = w / 6, p = w % 6;
  int k = kseg * 8;
  int c = k >> 10, rem = k & 1023, r = rem >> 5, x0 = rem & 31;
  int y = (pos / 7) * 32 + r;
  int xb = (pos % 7) * 32 + x0;
  int tly = tl[(b * 6 + p) * 2 + 0];
  int tlx = tl[(b * 6 + p) * 2 + 1];
  const float* im = img + (size_t)(b * 3 + c) * 448 * 448;
  unsigned short o8[8];
  if (p < 3) {
    const float* s = im + (size_t)(tly + y) * 448 + tlx + xb;
#pragma unroll
    for (int i = 0; i < 8; ++i) o8[i] = f2bf(s[i]);
  } else {
    const float f = 111.0f / 223.0f;
    float sy = tly + y * f;
    int y0 = (int)floorf(sy);
    float wy = sy - (float)y0;
    int y1 = y0 + 1 < 447 ? y0 + 1 : 447;
    const float* r0p = im + (size_t)y0 * 448;
    const float* r1p = im + (size_t)y1 * 448;
#pragma unroll
    for (int i = 0; i < 8; ++i) {
      float sx = tlx + (xb + i) * f;
      int x0i = (int)floorf(sx);
      float wx = sx - (float)x0i;
      int x1i = x0i + 1 < 447 ? x0i + 1 : 447;
      float v0 = r0p[x0i] * (1.f - wy) + r1p[x0i] * wy;
      float v1 = r0p[x1i] * (1.f - wy) + r1p[x1i] * wy;
      o8[i] = f2bf(v0 * (1.f - wx) + v1 * wx);
    }
  }
  *(uint4*)&win[(size_t)row * 3072 + k] = *(const uint4*)o8;
}

// ---------------- conv GEMM (m97 structure, 16x16x32) ----------------
template <int MODE, int WM>
__global__ __launch_bounds__(256) void gemm_conv(
    const unsigned short* __restrict__ A, const unsigned short* __restrict__ W,
    float* __restrict__ embOut, float* __restrict__ fm, int M) {
  constexpr int embBase = MODE ? 32 : 0;
  constexpr int BM = WM * 64;
  constexpr int WN = 4 / WM;
  constexpr int NC = 128 / WN / 16;
  constexpr int WCOL = 128 / WN;
  constexpr int ACH = BM / 32;
  __shared__ unsigned short sA[BM * 64];
  __shared__ unsigned short sB[128 * 64];
  const int t = threadIdx.x;
  const int nb = blockIdx.x, mb = blockIdx.y;
  const int lane = t & 63;
  const int lr = lane & 15, lk = lane >> 4;
  const int wv = t >> 6;
  const int wqr = wv / WN, wn = wv % WN;

  const unsigned short* gA[ACH];
  unsigned short* lA[ACH];
  const unsigned short* gB[4];
  unsigned short* lB[4];
#pragma unroll
  for (int j = 0; j < ACH; ++j) {
    int chunk = j * 256 + t;
    int row = chunk >> 3, seg = chunk & 7;
    int gseg = seg ^ (row & 7);
    int rg = mb * BM + row;
    if (rg > M - 1) rg = M - 1;
    gA[j] = A + (size_t)rg * 3072 + gseg * 8;
    lA[j] = &sA[chunk * 8];
  }
#pragma unroll
  for (int j = 0; j < 4; ++j) {
    int chunk = j * 256 + t;
    int row = chunk >> 3, seg = chunk & 7;
    int gseg = seg ^ (row & 7);
    gB[j] = W + (size_t)(nb * 128 + row) * 3072 + gseg * 8;
    lB[j] = &sB[chunk * 8];
  }

  f32x4 acc[4][NC] = {};
  for (int kb = 0; kb < 48; ++kb) {
    if (kb) __syncthreads();
#pragma unroll
    for (int j = 0; j < ACH; ++j) gload16(gA[j] + kb * 64, lA[j]);
#pragma unroll
    for (int j = 0; j < 4; ++j) gload16(gB[j] + kb * 64, lB[j]);
    __syncthreads();
#pragma unroll
    for (int ks = 0; ks < 2; ++ks) {
      s16x8 a[4], b[NC];
#pragma unroll
      for (int m = 0; m < 4; ++m) {
        int row = wqr * 64 + m * 16 + lr;
        int seg = ks * 4 + lk;
        a[m] = *(const s16x8*)&sA[row * 64 + ((seg ^ (row & 7)) * 8)];
      }
#pragma unroll
      for (int n = 0; n < NC; ++n) {
        int row = wn * WCOL + n * 16 + lr;
        int seg = ks * 4 + lk;
        b[n] = *(const s16x8*)&sB[row * 64 + ((seg ^ (row & 7)) * 8)];
      }
#pragma unroll
      for (int m = 0; m < 4; ++m)
#pragma unroll
        for (int n = 0; n < NC; ++n)
          acc[m][n] =
              __builtin_amdgcn_mfma_f32_16x16x32_bf16(a[m], b[n], acc[m][n], 0, 0, 0);
    }
  }

  float rv[4][NC][4];
#pragma unroll
  for (int m = 0; m < 4; ++m) {
    int base = mb * BM + wqr * 64 + m * 16;
#pragma unroll
    for (int e = 0; e < 4; ++e) {
      int r = base + lk * 4 + e;
      bool ok = (r < M);
#pragma unroll
      for (int n = 0; n < NC; ++n) {
        float v = acc[m][n][e];
        v = v > 0.f ? v : 0.f;
        rv[m][n][e] = ok ? v : 0.f;
      }
    }
  }

#pragma unroll
  for (int m = 0; m < 4; ++m) {
    int base = mb * BM + wqr * 64 + m * 16;
    if (base >= M) continue;
    int w0 = base / 49;
    int rtop = base + 15;
    if (rtop > M - 1) rtop = M - 1;
    int w1 = rtop / 49;
    for (int w = w0; w <= w1; ++w) {
#pragma unroll
      for (int n = 0; n < NC; ++n) {
        float s = 0.f;
#pragma unroll
        for (int e = 0; e < 4; ++e) {
          int r = base + lk * 4 + e;
          s += (r < M && (r / 49) == w) ? rv[m][n][e] : 0.f;
        }
        s += __shfl_xor(s, 16, 64);
        s += __shfl_xor(s, 32, 64);
        if (lk == 0)
          atomicAdd(&embOut[(size_t)(embBase + w) * 2048 + nb * 128 + wn * WCOL +
                            n * 16 + lr],
                    s * (1.0f / 49.0f));
      }
    }
  }

  if (MODE == 0) {
#pragma unroll
    for (int m = 0; m < 4; ++m) {
      int base = mb * BM + wqr * 64 + m * 16;
#pragma unroll
      for (int e = 0; e < 4; ++e) {
        int r = base + lk * 4 + e;
        float v = 0.f;
#pragma unroll
        for (int n = 0; n < NC; ++n) v += rv[m][n][e];
        v += __shfl_xor(v, 1, 64);
        v += __shfl_xor(v, 2, 64);
        v += __shfl_xor(v, 4, 64);
        v += __shfl_xor(v, 8, 64);
        if (lr == 0 && r < M) atomicAdd(&fm[r], v);
      }
    }
  }
}

// ---------------- coordinates (NMS peak picking) ----------------
__global__ void coords_kernel(const float* __restrict__ fm,
                              const float* __restrict__ scale,
                              int* __restrict__ tl) {
  int b = blockIdx.x, t = threadIdx.x;
  __shared__ float fs[49];
  if (t < 49) fs[t] = fm[b * 49 + t];
  __syncthreads();
  if (t != 0) return;
  int s0 = (int)scale[b * 2 + 0], s1 = (int)scale[b * 2 + 1];
  int smin = s0 < s1 ? s0 : s1;
  int base_y = (s0 - smin) / 2, base_x = (s1 - smin) / 2;
  float sc[36];
  for (int f = 0; f < 2; ++f) {
    int kk = (f == 0) ? 3 : 2;
    int sw = 8 - kk;
    int psz = (f == 0) ? 224 : 112;
    int half = psz / 2;
    for (int iy = 0; iy < sw; ++iy)
      for (int ix = 0; ix < sw; ++ix) {
        float s = 0.f;
        for (int dy = 0; dy < kk; ++dy)
          for (int dx = 0; dx < kk; ++dx) s += fs[(iy + dy) * 7 + ix + dx];
        sc[iy * sw + ix] = s / (float)(kk * kk);
      }
    for (int it = 0; it < 3; ++it) {
      float best = -1e30f;
      int bi = 0;
      for (int i = 0; i < sw * sw; ++i)
        if (sc[i] > best) { best = sc[i]; bi = i; }
      int ly = bi / sw, lx = bi % sw;
      for (int dy = -1; dy <= 1; ++dy)
        for (int dx = -1; dx <= 1; ++dx) {
          int ny = ly + dy, nx = lx + dx;
          if (ny >= 0 && ny < sw && nx >= 0 && nx < sw) sc[ny * sw + nx] = 0.f;
        }
      float rh = (2 * ly + 7 - sw + 1) / 14.0f;
      float rw = (2 * lx + 7 - sw + 1) / 14.0f;
      int cy = (int)(base_y + smin * rh);
      int cx = (int)(base_x + smin * rw);
      int tly = cy - half, bry = cy + half;
      int tlx = cx - half, brx = cx + half;
      int below = tly < 0 ? tly : 0; bry -= below; tly -= below;
      int over = bry - s0 > 0 ? bry - s0 : 0; tly -= over; bry -= over;
      tly = tly > 0 ? tly : 0;
      below = tlx < 0 ? tlx : 0; brx -= below; tlx -= below;
      over = brx - s1 > 0 ? brx - s1 : 0; tlx -= over; brx -= over;
      tlx = tlx > 0 ? tlx : 0;
      int slot = f * 3 + it;
      tl[(b * 6 + slot) * 2 + 0] = tly;
      tl[(b * 6 + slot) * 2 + 1] = tlx;
    }
  }
}

// ---------------- gemm7 helper for SA ----------------
template <int NCOLS, int RELU, bool RES>
__device__ __forceinline__ void gemm7(const float* __restrict__ X,
                                      const float* __restrict__ WT,
                                      const float* __restrict__ bias,
                                      const float* __restrict__ res,
                                      float* __restrict__ Y, int t) {
  int wv = t >> 6, lane = t & 63;
  int c_off = lane & 15, kq = lane >> 4;
  const int NCH = NCOLS / 16;
  for (int ch = wv; ch < NCH; ch += 16) {
    int c = ch * 16 + c_off;
    float s[7] = {0.f, 0.f, 0.f, 0.f, 0.f, 0.f, 0.f};
    const float* wp = WT + kq * 32 * NCOLS + c;
#pragma unroll 4
    for (int j = 0; j < 8; ++j) {
      float w0 = wp[(4 * j + 0) * NCOLS];
      float w1 = wp[(4 * j + 1) * NCOLS];
      float w2 = wp[(4 * j + 2) * NCOLS];
      float w3 = wp[(4 * j + 3) * NCOLS];
#pragma unroll
      for (int l = 0; l < 7; ++l) {
        float4 xv = *(const float4*)&X[l * 128 + kq * 32 + 4 * j];
        s[l] = fmaf(xv.x, w0, s[l]);
        s[l] = fmaf(xv.y, w1, s[l]);
        s[l] = fmaf(xv.z, w2, s[l]);
        s[l] = fmaf(xv.w, w3, s[l]);
      }
    }
#pragma unroll
    for (int l = 0; l < 7; ++l) {
      s[l] += __shfl_xor(s[l], 16, 64);
      s[l] += __shfl_xor(s[l], 32, 64);
    }
    if (lane < 16) {
      float bv = bias[c];
#pragma unroll
      for (int l = 0; l < 7; ++l) {
        float v = s[l] + bv;
        if (RES) v += res[l * 128 + c];
        if (RELU) v = v > 0.f ? v : 0.f;
        Y[l * NCOLS + c] = v;
      }
    }
  }
}

// ---------------- fc1 (fused) + 3x SA layers + final fc ----------------
// Round-13 SA structure (proven); entry phase computes fc1 in-block:
// block b stages its 7 emb rows (6 windows + whole) in LDS, 1024 threads as
// (d 0..127) x (kq 0..7), 8-way K-split, shfl reduce over kq (lane bits 0..2).
__global__ __launch_bounds__(1024) void sa_kernel(
    const float* __restrict__ emb, const float* __restrict__ fc1T,
    const float* __restrict__ fc1_b, const float* __restrict__ inT,
    const float* __restrict__ in_b, const float* __restrict__ outT,
    const float* __restrict__ out_b, const float* __restrict__ ln1w,
    const float* __restrict__ ln1b, const float* __restrict__ f1T,
    const float* __restrict__ f1b, const float* __restrict__ f2T,
    const float* __restrict__ f2b, const float* __restrict__ ln2w,
    const float* __restrict__ ln2b, const float* __restrict__ fcw,
    const float* __restrict__ fcb, float* __restrict__ out) {
  int b = blockIdx.x, t = threadIdx.x;
  __shared__ float e7[7][2048];
  __shared__ float x[7][128], qkv[7][384], att[4][7][7], ybuf[7][128], tmp[7][128];
  __shared__ float mu[7], inv[7];
  // stage 7 emb rows: tokens 0..5 = windows (emb rows 32+b*6+l), token 6 = whole (row b)
  for (int idx = t; idx < 3584; idx += 1024) {
    int l = idx >> 9, j = idx & 511;
    int srcrow = (l == 6) ? b : (32 + b * 6 + l);
    ((float4*)e7[l])[j] = ((const float4*)(emb + (size_t)srcrow * 2048))[j];
  }
  __syncthreads();
  // fc1 + relu -> x[l][d].  t = d*8 + kq.
  {
    int d = t >> 3, kq = t & 7;
    for (int l = 0; l < 7; ++l) {
      const float4* ep = (const float4*)&e7[l][kq * 256];
      const float* wp = fc1T + (size_t)(kq * 256) * 128 + d;
      float s = 0.f;
#pragma unroll 8
      for (int j = 0; j < 64; ++j) {
        float4 ev = ep[j];
        s = fmaf(ev.x, wp[(4 * j + 0) * 128], s);
        s = fmaf(ev.y, wp[(4 * j + 1) * 128], s);
        s = fmaf(ev.z, wp[(4 * j + 2) * 128], s);
        s = fmaf(ev.w, wp[(4 * j + 3) * 128], s);
      }
      s += __shfl_xor(s, 1, 64);
      s += __shfl_xor(s, 2, 64);
      s += __shfl_xor(s, 4, 64);
      if (kq == 0) {
        float v = s + fc1_b[d];
        x[l][d] = v > 0.f ? v : 0.f;
      }
    }
  }
  __syncthreads();
  for (int layer = 0; layer < 3; ++layer) {
    gemm7<384, 0, false>(&x[0][0], inT + layer * 384 * 128, in_b + layer * 384,
                         nullptr, &qkv[0][0], t);
    __syncthreads();
    if (t < 196) {
      int h = t / 49, l = (t % 49) / 7, m = t % 7;
      const float4* qr = (const float4*)&qkv[l][h * 32];
      const float4* kr = (const float4*)&qkv[m][128 + h * 32];
      float s = 0.f;
#pragma unroll
      for (int d = 0; d < 8; ++d) {
        float4 a = qr[d], c = kr[d];
        s += a.x * c.x + a.y * c.y + a.z * c.z + a.w * c.w;
      }
      att[h][l][m] = s * 0.17677669529663687f;
    }
    __syncthreads();
    if (t < 28) {
      int h = t / 7, l = t % 7;
      float mx = att[h][l][0];
      for (int m = 1; m < 7; ++m) mx = fmaxf(mx, att[h][l][m]);
      float s = 0.f;
      float e[7];
      for (int m = 0; m < 7; ++m) { e[m] = expf(att[h][l][m] - mx); s += e[m]; }
      float r = 1.0f / s;
      for (int m = 0; m < 7; ++m) att[h][l][m] = e[m] * r;
    }
    __syncthreads();
    if (t < 896) {
      int l = t / 128, d = t % 128, h = d / 32;
      float s = 0.f;
#pragma unroll
      for (int m = 0; m < 7; ++m) s += att[h][l][m] * qkv[m][256 + d];
      ybuf[l][d] = s;
    }
    __syncthreads();
    gemm7<128, 0, true>(&ybuf[0][0], outT + layer * 128 * 128,
                        out_b + layer * 128, &x[0][0], &tmp[0][0], t);
    __syncthreads();
    if (t < 448) {
      int row = t >> 6, lane = t & 63;
      float a = tmp[row][lane], c2 = tmp[row][lane + 64];
      float s = a + c2;
      for (int o = 1; o < 64; o <<= 1) s += __shfl_xor(s, o, 64);
      float m = s * (1.0f / 128.0f);
      float d1 = a - m, d2 = c2 - m;
      float v = d1 * d1 + d2 * d2;
      for (int o = 1; o < 64; o <<= 1) v += __shfl_xor(v, o, 64);
      if (lane == 0) { mu[row] = m; inv[row] = 1.0f / sqrtf(v * (1.0f / 128.0f) + 1e-5f); }
    }
    __syncthreads();
    if (t < 896) {
      int l = t / 128, d = t % 128;
      x[l][d] = (tmp[l][d] - mu[l]) * inv[l] * ln1w[layer * 128 + d] +
                ln1b[layer * 128 + d];
    }
    __syncthreads();
    gemm7<128, 1, false>(&x[0][0], f1T + layer * 128 * 128, f1b + layer * 128,
                         nullptr, &ybuf[0][0], t);
    __syncthreads();
    gemm7<128, 0, true>(&ybuf[0][0], f2T + layer * 128 * 128, f2b + layer * 128,
                        &x[0][0], &tmp[0][0], t);
    __syncthreads();
    if (t < 448) {
      int row = t >> 6, lane = t & 63;
      float a = tmp[row][lane], c2 = tmp[row][lane + 64];
      float s = a + c2;
      for (int o = 1; o < 64; o <<= 1) s += __shfl_xor(s, o, 64);
      float m = s * (1.0f / 128.0f);
      float d1 = a - m, d2 = c2 - m;
      float v = d1 * d1 + d2 * d2;
      for (int o = 1; o < 64; o <<= 1) v += __shfl_xor(v, o, 64);
      if (lane == 0) { mu[row] = m; inv[row] = 1.0f / sqrtf(v * (1.0f / 128.0f) + 1e-5f); }
    }
    __syncthreads();
    if (t < 896) {
      int l = t / 128, d = t % 128;
      x[l][d] = (tmp[l][d] - mu[l]) * inv[l] * ln2w[layer * 128 + d] +
                ln2b[layer * 128 + d];
    }
    __syncthreads();
  }
  if (t < 64) {
    float s = x[6][t] * fcw[t] + x[6][t + 64] * fcw[t + 64];
    for (int o = 1; o < 64; o <<= 1) s += __shfl_xor(s, o, 64);
    if (t == 0) out[b] = s + fcb[0];
  }
}

extern "C" void kernel_launch(void* const* d_in, const int* in_sizes, int n_in,
                              void* d_out, int out_size, void* d_ws, size_t ws_size,
                              hipStream_t stream) {
  (void)in_sizes; (void)n_in; (void)out_size; (void)ws_size;
  const float* input_img = (const float*)d_in[0];
  const float* cropped = (const float*)d_in[1];
  const float* scale = (const float*)d_in[2];
  const float* conv_w = (const float*)d_in[3];
  const float* fc1_w = (const float*)d_in[4];
  const float* fc1_b = (const float*)d_in[5];
  const float* fc_w = (const float*)d_in[6];
  const float* fc_b = (const float*)d_in[7];
  const float* sa_in_w = (const float*)d_in[8];
  const float* sa_in_b = (const float*)d_in[9];
  const float* sa_out_w = (const float*)d_in[10];
  const float* sa_out_b = (const float*)d_in[11];
  const float* sa_ln1_w = (const float*)d_in[12];
  const float* sa_ln1_b = (const float*)d_in[13];
  const float* sa_fc1_w = (const float*)d_in[14];
  const float* sa_fc1_b = (const float*)d_in[15];
  const float* sa_fc2_w = (const float*)d_in[16];
  const float* sa_fc2_b = (const float*)d_in[17];
  const float* sa_ln2_w = (const float*)d_in[18];
  const float* sa_ln2_b = (const float*)d_in[19];

  char* ws = (char*)d_ws;
  size_t off = 0;
  auto alloc = [&](size_t bytes) -> void* {
    void* p = ws + off;
    off = (off + bytes + 255) & ~(size_t)255;
    return p;
  };
  unsigned short* whi = (unsigned short*)alloc(2048L * 3072 * 2);
  unsigned short* apat = (unsigned short*)alloc(1568L * 3072 * 2);
  unsigned short* winbuf = (unsigned short*)alloc(9408L * 3072 * 2);
  float* emb = (float*)alloc(224L * 2048 * 4);  // 1835008 B (256-aligned)
  float* fm = (float*)alloc(1568L * 4);         // contiguous after emb
  int* tlbuf = (int*)alloc(32L * 6 * 2 * 4);
  float* fc1T = (float*)alloc(2048L * 128 * 4);
  float* inT = (float*)alloc(3L * 384 * 128 * 4);
  float* outT = (float*)alloc(3L * 128 * 128 * 4);
  float* f1T = (float*)alloc(3L * 128 * 128 * 4);
  float* f2T = (float*)alloc(3L * 128 * 128 * 4);

  // prep: bf16 conversions + patchify + transposes + zero emb/fm (one dispatch)
  prep_kernel<<<6418, 256, 0, stream>>>(conv_w, whi, cropped, apat, fc1_w, fc1T,
                                        sa_in_w, inT, sa_out_w, outT, sa_fc1_w,
                                        f1T, sa_fc2_w, f2T, emb);

  // cropped conv: BM=64 (400 blocks), fused relu+GAP(emb rows 0..31)+fm
  gemm_conv<0, 1><<<dim3(16, 25), 256, 0, stream>>>(apat, whi, emb, fm, 1568);
  coords_kernel<<<32, 64, 0, stream>>>(fm, scale, tlbuf);
  gather_windows<<<14112, 256, 0, stream>>>(input_img, tlbuf, winbuf);
  // windows conv: BM=128 (proven config), fused relu+GAP(emb rows 32..223)
  gemm_conv<1, 2><<<dim3(16, 74), 256, 0, stream>>>(winbuf, whi, emb, nullptr, 9408);
  // fc1 fused into sa_kernel (one dispatch, no all_emb round-trip)
  sa_kernel<<<32, 1024, 0, stream>>>(emb, fc1T, fc1_b, inT, sa_in_b, outT,
                                     sa_out_b, sa_ln1_w, sa_ln1_b, f1T, sa_fc1_b,
                                     f2T, sa_fc2_b, sa_ln2_w, sa_ln2_b,
                                     fc_w, fc_b, (float*)d_out);
}

// Round 16
// 356.165 us; speedup vs baseline: 2.0339x; 2.0339x over previous
//
#include <hip/hip_runtime.h>

typedef __attribute__((ext_vector_type(8))) short s16x8;
typedef __attribute__((ext_vector_type(4))) float f32x4;

__device__ __forceinline__ unsigned short f2bf(float x) {
  unsigned int u = __float_as_uint(x);
  u += 0x7FFFu + ((u >> 16) & 1u);
  return (unsigned short)(u >> 16);
}

__device__ __forceinline__ void gload16(const unsigned short* g, unsigned short* l) {
  __builtin_amdgcn_global_load_lds(
      (const __attribute__((address_space(1))) void*)g,
      (__attribute__((address_space(3))) void*)l, 16, 0, 0);
}

// ---------------- merged prep: weights->bf16, patchify, transposes, zero-fill ----
__global__ __launch_bounds__(256) void prep_kernel(
    const float* __restrict__ conv_w, unsigned short* __restrict__ whi,
    const float* __restrict__ cropped, unsigned short* __restrict__ apat,
    const float* __restrict__ fc1_w, float* __restrict__ fc1T,
    const float* __restrict__ in_w, float* __restrict__ inT,
    const float* __restrict__ out_w, float* __restrict__ outT,
    const float* __restrict__ f1w, float* __restrict__ f1T,
    const float* __restrict__ f2w, float* __restrict__ f2T,
    float* __restrict__ emb_zero) {
  __shared__ float tile[32][33];
  int blk = blockIdx.x;
  int t = threadIdx.x;
  if (blk < 3072) {
    int idx = blk * 256 + t;  // 2048*384
    const float4* s = (const float4*)(conv_w + (size_t)idx * 8);
    float4 v0 = s[0], v1 = s[1];
    unsigned short h8[8] = {f2bf(v0.x), f2bf(v0.y), f2bf(v0.z), f2bf(v0.w),
                            f2bf(v1.x), f2bf(v1.y), f2bf(v1.z), f2bf(v1.w)};
    *(uint4*)&whi[(size_t)idx * 8] = *(const uint4*)h8;
    return;
  }
  if (blk < 5424) {
    int idx = (blk - 3072) * 256 + t;  // 1568*384
    if (idx >= 1568 * 384) return;
    int kseg = idx % 384, row = idx / 384;
    int img = row / 49, pos = row % 49;
    int k = kseg * 8;
    int c = k >> 10, rem = k & 1023, r = rem >> 5, x0 = rem & 31;
    const float* s =
        cropped + ((size_t)(img * 3 + c) * 224 + (pos / 7) * 32 + r) * 224 +
        (pos % 7) * 32 + x0;
    float4 v0 = *(const float4*)(s);
    float4 v1 = *(const float4*)(s + 4);
    unsigned short h8[8] = {f2bf(v0.x), f2bf(v0.y), f2bf(v0.z), f2bf(v0.w),
                            f2bf(v1.x), f2bf(v1.y), f2bf(v1.z), f2bf(v1.w)};
    *(uint4*)&apat[(size_t)row * 3072 + k] = *(const uint4*)h8;
    return;
  }
  if (blk >= 5968) {
    int idx = (blk - 5968) * 256 + t;  // 115080 float4s
    if (idx < 115080) ((float4*)emb_zero)[idx] = (float4){0.f, 0.f, 0.f, 0.f};
    return;
  }
  int id = blk - 5424;  // 544 transpose blocks
  const float* src;
  float* dst;
  int R, C, bx, by;
  if (id < 256) {
    src = fc1_w; dst = fc1T; R = 128; C = 2048; bx = id % 64; by = id / 64;
  } else if (id < 400) {
    id -= 256;
    int z = id / 48, r = id % 48;
    src = in_w + z * 384 * 128; dst = inT + z * 384 * 128;
    R = 384; C = 128; bx = r % 4; by = r / 4;
  } else {
    id -= 400;
    int which = id / 48;  // 0=out, 1=f1, 2=f2
    id -= which * 48;
    int z = id / 16, r = id % 16;
    const float* s3[3] = {out_w, f1w, f2w};
    float* d3[3] = {outT, f1T, f2T};
    src = s3[which] + z * 128 * 128; dst = d3[which] + z * 128 * 128;
    R = 128; C = 128; bx = r % 4; by = r / 4;
  }
  int tx = t & 31, ty = t >> 5;  // 32 x 8
#pragma unroll
  for (int i = 0; i < 32; i += 8) {
    int r = by * 32 + ty + i, c = bx * 32 + tx;
    if (r < R && c < C) tile[ty + i][tx] = src[(size_t)r * C + c];
  }
  __syncthreads();
#pragma unroll
  for (int i = 0; i < 32; i += 8) {
    int r = bx * 32 + ty + i, c = by * 32 + tx;
    if (r < C && c < R) dst[(size_t)r * R + c] = tile[tx][ty + i];
  }
}

// ---------------- window crop/resize -> patchified bf16 [9408][3072] ----------------
__global__ __launch_bounds__(256) void gather_windows(
    const float* __restrict__ img, const int* __restrict__ tl,
    unsigned short* __restrict__ win) {
  int idx = blockIdx.x * 256 + threadIdx.x;  // 9408*384
  if (idx >= 9408 * 384) return;
  int kseg = idx % 384, row = idx / 384;
  int w = row / 49, pos = row % 49;
  int b = w / 6, p = w % 6;
  int k = kseg * 8;
  int c = k >> 10, rem = k & 1023, r = rem >> 5, x0 = rem & 31;
  int y = (pos / 7) * 32 + r;
  int xb = (pos % 7) * 32 + x0;
  int tly = tl[(b * 6 + p) * 2 + 0];
  int tlx = tl[(b * 6 + p) * 2 + 1];
  const float* im = img + (size_t)(b * 3 + c) * 448 * 448;
  unsigned short o8[8];
  if (p < 3) {
    const float* s = im + (size_t)(tly + y) * 448 + tlx + xb;
#pragma unroll
    for (int i = 0; i < 8; ++i) o8[i] = f2bf(s[i]);
  } else {
    const float f = 111.0f / 223.0f;
    float sy = tly + y * f;
    int y0 = (int)floorf(sy);
    float wy = sy - (float)y0;
    int y1 = y0 + 1 < 447 ? y0 + 1 : 447;
    const float* r0p = im + (size_t)y0 * 448;
    const float* r1p = im + (size_t)y1 * 448;
#pragma unroll
    for (int i = 0; i < 8; ++i) {
      float sx = tlx + (xb + i) * f;
      int x0i = (int)floorf(sx);
      float wx = sx - (float)x0i;
      int x1i = x0i + 1 < 447 ? x0i + 1 : 447;
      float v0 = r0p[x0i] * (1.f - wy) + r1p[x0i] * wy;
      float v1 = r0p[x1i] * (1.f - wy) + r1p[x1i] * wy;
      o8[i] = f2bf(v0 * (1.f - wx) + v1 * wx);
    }
  }
  *(uint4*)&win[(size_t)row * 3072 + k] = *(const uint4*)o8;
}

// ---------------- conv GEMM (m97 structure, 16x16x32) ----------------
template <int MODE, int WM>
__global__ __launch_bounds__(256) void gemm_conv(
    const unsigned short* __restrict__ A, const unsigned short* __restrict__ W,
    float* __restrict__ embOut, float* __restrict__ fm, int M) {
  constexpr int embBase = MODE ? 32 : 0;
  constexpr int BM = WM * 64;
  constexpr int WN = 4 / WM;
  constexpr int NC = 128 / WN / 16;
  constexpr int WCOL = 128 / WN;
  constexpr int ACH = BM / 32;
  __shared__ unsigned short sA[BM * 64];
  __shared__ unsigned short sB[128 * 64];
  const int t = threadIdx.x;
  const int nb = blockIdx.x, mb = blockIdx.y;
  const int lane = t & 63;
  const int lr = lane & 15, lk = lane >> 4;
  const int wv = t >> 6;
  const int wqr = wv / WN, wn = wv % WN;

  const unsigned short* gA[ACH];
  unsigned short* lA[ACH];
  const unsigned short* gB[4];
  unsigned short* lB[4];
#pragma unroll
  for (int j = 0; j < ACH; ++j) {
    int chunk = j * 256 + t;
    int row = chunk >> 3, seg = chunk & 7;
    int gseg = seg ^ (row & 7);
    int rg = mb * BM + row;
    if (rg > M - 1) rg = M - 1;
    gA[j] = A + (size_t)rg * 3072 + gseg * 8;
    lA[j] = &sA[chunk * 8];
  }
#pragma unroll
  for (int j = 0; j < 4; ++j) {
    int chunk = j * 256 + t;
    int row = chunk >> 3, seg = chunk & 7;
    int gseg = seg ^ (row & 7);
    gB[j] = W + (size_t)(nb * 128 + row) * 3072 + gseg * 8;
    lB[j] = &sB[chunk * 8];
  }

  f32x4 acc[4][NC] = {};
  for (int kb = 0; kb < 48; ++kb) {
    if (kb) __syncthreads();
#pragma unroll
    for (int j = 0; j < ACH; ++j) gload16(gA[j] + kb * 64, lA[j]);
#pragma unroll
    for (int j = 0; j < 4; ++j) gload16(gB[j] + kb * 64, lB[j]);
    __syncthreads();
#pragma unroll
    for (int ks = 0; ks < 2; ++ks) {
      s16x8 a[4], b[NC];
#pragma unroll
      for (int m = 0; m < 4; ++m) {
        int row = wqr * 64 + m * 16 + lr;
        int seg = ks * 4 + lk;
        a[m] = *(const s16x8*)&sA[row * 64 + ((seg ^ (row & 7)) * 8)];
      }
#pragma unroll
      for (int n = 0; n < NC; ++n) {
        int row = wn * WCOL + n * 16 + lr;
        int seg = ks * 4 + lk;
        b[n] = *(const s16x8*)&sB[row * 64 + ((seg ^ (row & 7)) * 8)];
      }
#pragma unroll
      for (int m = 0; m < 4; ++m)
#pragma unroll
        for (int n = 0; n < NC; ++n)
          acc[m][n] =
              __builtin_amdgcn_mfma_f32_16x16x32_bf16(a[m], b[n], acc[m][n], 0, 0, 0);
    }
  }

  float rv[4][NC][4];
#pragma unroll
  for (int m = 0; m < 4; ++m) {
    int base = mb * BM + wqr * 64 + m * 16;
#pragma unroll
    for (int e = 0; e < 4; ++e) {
      int r = base + lk * 4 + e;
      bool ok = (r < M);
#pragma unroll
      for (int n = 0; n < NC; ++n) {
        float v = acc[m][n][e];
        v = v > 0.f ? v : 0.f;
        rv[m][n][e] = ok ? v : 0.f;
      }
    }
  }

#pragma unroll
  for (int m = 0; m < 4; ++m) {
    int base = mb * BM + wqr * 64 + m * 16;
    if (base >= M) continue;
    int w0 = base / 49;
    int rtop = base + 15;
    if (rtop > M - 1) rtop = M - 1;
    int w1 = rtop / 49;
    for (int w = w0; w <= w1; ++w) {
#pragma unroll
      for (int n = 0; n < NC; ++n) {
        float s = 0.f;
#pragma unroll
        for (int e = 0; e < 4; ++e) {
          int r = base + lk * 4 + e;
          s += (r < M && (r / 49) == w) ? rv[m][n][e] : 0.f;
        }
        s += __shfl_xor(s, 16, 64);
        s += __shfl_xor(s, 32, 64);
        if (lk == 0)
          atomicAdd(&embOut[(size_t)(embBase + w) * 2048 + nb * 128 + wn * WCOL +
                            n * 16 + lr],
                    s * (1.0f / 49.0f));
      }
    }
  }

  if (MODE == 0) {
#pragma unroll
    for (int m = 0; m < 4; ++m) {
      int base = mb * BM + wqr * 64 + m * 16;
#pragma unroll
      for (int e = 0; e < 4; ++e) {
        int r = base + lk * 4 + e;
        float v = 0.f;
#pragma unroll
        for (int n = 0; n < NC; ++n) v += rv[m][n][e];
        v += __shfl_xor(v, 1, 64);
        v += __shfl_xor(v, 2, 64);
        v += __shfl_xor(v, 4, 64);
        v += __shfl_xor(v, 8, 64);
        if (lr == 0 && r < M) atomicAdd(&fm[r], v);
      }
    }
  }
}

// ---------------- coordinates (NMS peak picking) ----------------
__global__ void coords_kernel(const float* __restrict__ fm,
                              const float* __restrict__ scale,
                              int* __restrict__ tl) {
  int b = blockIdx.x, t = threadIdx.x;
  __shared__ float fs[49];
  if (t < 49) fs[t] = fm[b * 49 + t];
  __syncthreads();
  if (t != 0) return;
  int s0 = (int)scale[b * 2 + 0], s1 = (int)scale[b * 2 + 1];
  int smin = s0 < s1 ? s0 : s1;
  int base_y = (s0 - smin) / 2, base_x = (s1 - smin) / 2;
  float sc[36];
  for (int f = 0; f < 2; ++f) {
    int kk = (f == 0) ? 3 : 2;
    int sw = 8 - kk;
    int psz = (f == 0) ? 224 : 112;
    int half = psz / 2;
    for (int iy = 0; iy < sw; ++iy)
      for (int ix = 0; ix < sw; ++ix) {
        float s = 0.f;
        for (int dy = 0; dy < kk; ++dy)
          for (int dx = 0; dx < kk; ++dx) s += fs[(iy + dy) * 7 + ix + dx];
        sc[iy * sw + ix] = s / (float)(kk * kk);
      }
    for (int it = 0; it < 3; ++it) {
      float best = -1e30f;
      int bi = 0;
      for (int i = 0; i < sw * sw; ++i)
        if (sc[i] > best) { best = sc[i]; bi = i; }
      int ly = bi / sw, lx = bi % sw;
      for (int dy = -1; dy <= 1; ++dy)
        for (int dx = -1; dx <= 1; ++dx) {
          int ny = ly + dy, nx = lx + dx;
          if (ny >= 0 && ny < sw && nx >= 0 && nx < sw) sc[ny * sw + nx] = 0.f;
        }
      float rh = (2 * ly + 7 - sw + 1) / 14.0f;
      float rw = (2 * lx + 7 - sw + 1) / 14.0f;
      int cy = (int)(base_y + smin * rh);
      int cx = (int)(base_x + smin * rw);
      int tly = cy - half, bry = cy + half;
      int tlx = cx - half, brx = cx + half;
      int below = tly < 0 ? tly : 0; bry -= below; tly -= below;
      int over = bry - s0 > 0 ? bry - s0 : 0; tly -= over; bry -= over;
      tly = tly > 0 ? tly : 0;
      below = tlx < 0 ? tlx : 0; brx -= below; tlx -= below;
      over = brx - s1 > 0 ? brx - s1 : 0; tlx -= over; brx -= over;
      tlx = tlx > 0 ? tlx : 0;
      int slot = f * 3 + it;
      tl[(b * 6 + slot) * 2 + 0] = tly;
      tl[(b * 6 + slot) * 2 + 1] = tlx;
    }
  }
}

// ---------------- fc1 + relu + reorg to all_emb[32,7,128] ----------------
__global__ __launch_bounds__(512) void fc1_kernel(const float* __restrict__ emb,
                                                  const float* __restrict__ wT,
                                                  const float* __restrict__ bias,
                                                  float* __restrict__ all_emb) {
  int i = blockIdx.x;
  __shared__ float e[2048];
  int t = threadIdx.x;
  ((float4*)e)[t] = ((const float4*)(emb + (size_t)i * 2048))[t];
  __syncthreads();
  int wv = t >> 6, lane = t & 63;
  int c_off = lane & 15, kq = lane >> 4;
  int c = wv * 16 + c_off;
  float s = 0.f;
  const float* wp = wT + (size_t)kq * 512 * 128 + c;
  const float4* ep = (const float4*)(e + kq * 512);
#pragma unroll 4
  for (int j = 0; j < 128; ++j) {
    float4 ev = ep[j];
    s = fmaf(ev.x, wp[(4 * j + 0) * 128], s);
    s = fmaf(ev.y, wp[(4 * j + 1) * 128], s);
    s = fmaf(ev.z, wp[(4 * j + 2) * 128], s);
    s = fmaf(ev.w, wp[(4 * j + 3) * 128], s);
  }
  s += __shfl_xor(s, 16, 64);
  s += __shfl_xor(s, 32, 64);
  if (lane < 16) {
    float v = s + bias[c];
    v = v > 0.f ? v : 0.f;
    int dst;
    if (i < 32) dst = i * 7 + 6;
    else { int wd = i - 32; dst = (wd / 6) * 7 + (wd % 6); }
    all_emb[dst * 128 + c] = v;
  }
}

// ---------------- gemm7 helper for SA ----------------
template <int NCOLS, int RELU, bool RES>
__device__ __forceinline__ void gemm7(const float* __restrict__ X,
                                      const float* __restrict__ WT,
                                      const float* __restrict__ bias,
                                      const float* __restrict__ res,
                                      float* __restrict__ Y, int t) {
  int wv = t >> 6, lane = t & 63;
  int c_off = lane & 15, kq = lane >> 4;
  const int NCH = NCOLS / 16;
  for (int ch = wv; ch < NCH; ch += 16) {
    int c = ch * 16 + c_off;
    float s[7] = {0.f, 0.f, 0.f, 0.f, 0.f, 0.f, 0.f};
    const float* wp = WT + kq * 32 * NCOLS + c;
#pragma unroll 4
    for (int j = 0; j < 8; ++j) {
      float w0 = wp[(4 * j + 0) * NCOLS];
      float w1 = wp[(4 * j + 1) * NCOLS];
      float w2 = wp[(4 * j + 2) * NCOLS];
      float w3 = wp[(4 * j + 3) * NCOLS];
#pragma unroll
      for (int l = 0; l < 7; ++l) {
        float4 xv = *(const float4*)&X[l * 128 + kq * 32 + 4 * j];
        s[l] = fmaf(xv.x, w0, s[l]);
        s[l] = fmaf(xv.y, w1, s[l]);
        s[l] = fmaf(xv.z, w2, s[l]);
        s[l] = fmaf(xv.w, w3, s[l]);
      }
    }
#pragma unroll
    for (int l = 0; l < 7; ++l) {
      s[l] += __shfl_xor(s[l], 16, 64);
      s[l] += __shfl_xor(s[l], 32, 64);
    }
    if (lane < 16) {
      float bv = bias[c];
#pragma unroll
      for (int l = 0; l < 7; ++l) {
        float v = s[l] + bv;
        if (RES) v += res[l * 128 + c];
        if (RELU) v = v > 0.f ? v : 0.f;
        Y[l * NCOLS + c] = v;
      }
    }
  }
}

// ---------------- 3x SA layers + final fc ----------------
__global__ __launch_bounds__(1024) void sa_kernel(
    const float* __restrict__ all_emb, const float* __restrict__ inT,
    const float* __restrict__ in_b, const float* __restrict__ outT,
    const float* __restrict__ out_b, const float* __restrict__ ln1w,
    const float* __restrict__ ln1b, const float* __restrict__ f1T,
    const float* __restrict__ f1b, const float* __restrict__ f2T,
    const float* __restrict__ f2b, const float* __restrict__ ln2w,
    const float* __restrict__ ln2b, const float* __restrict__ fcw,
    const float* __restrict__ fcb, float* __restrict__ out) {
  int b = blockIdx.x, t = threadIdx.x;
  __shared__ float x[7][128], qkv[7][384], att[4][7][7], ybuf[7][128], tmp[7][128];
  __shared__ float mu[7], inv[7];
  if (t < 896) x[t / 128][t % 128] = all_emb[b * 896 + t];
  __syncthreads();
  for (int layer = 0; layer < 3; ++layer) {
    gemm7<384, 0, false>(&x[0][0], inT + layer * 384 * 128, in_b + layer * 384,
                         nullptr, &qkv[0][0], t);
    __syncthreads();
    if (t < 196) {
      int h = t / 49, l = (t % 49) / 7, m = t % 7;
      const float4* qr = (const float4*)&qkv[l][h * 32];
      const float4* kr = (const float4*)&qkv[m][128 + h * 32];
      float s = 0.f;
#pragma unroll
      for (int d = 0; d < 8; ++d) {
        float4 a = qr[d], c = kr[d];
        s += a.x * c.x + a.y * c.y + a.z * c.z + a.w * c.w;
      }
      att[h][t % 49 / 7][t % 7] = s * 0.17677669529663687f;
    }
    __syncthreads();
    if (t < 28) {
      int h = t / 7, l = t % 7;
      float mx = att[h][l][0];
      for (int m = 1; m < 7; ++m) mx = fmaxf(mx, att[h][l][m]);
      float s = 0.f;
      float e[7];
      for (int m = 0; m < 7; ++m) { e[m] = expf(att[h][l][m] - mx); s += e[m]; }
      float r = 1.0f / s;
      for (int m = 0; m < 7; ++m) att[h][l][m] = e[m] * r;
    }
    __syncthreads();
    if (t < 896) {
      int l = t / 128, d = t % 128, h = d / 32;
      float s = 0.f;
#pragma unroll
      for (int m = 0; m < 7; ++m) s += att[h][l][m] * qkv[m][256 + d];
      ybuf[l][d] = s;
    }
    __syncthreads();
    gemm7<128, 0, true>(&ybuf[0][0], outT + layer * 128 * 128,
                        out_b + layer * 128, &x[0][0], &tmp[0][0], t);
    __syncthreads();
    if (t < 448) {
      int row = t >> 6, lane = t & 63;
      float a = tmp[row][lane], c2 = tmp[row][lane + 64];
      float s = a + c2;
      for (int o = 1; o < 64; o <<= 1) s += __shfl_xor(s, o, 64);
      float m = s * (1.0f / 128.0f);
      float d1 = a - m, d2 = c2 - m;
      float v = d1 * d1 + d2 * d2;
      for (int o = 1; o < 64; o <<= 1) v += __shfl_xor(v, o, 64);
      if (lane == 0) { mu[row] = m; inv[row] = 1.0f / sqrtf(v * (1.0f / 128.0f) + 1e-5f); }
    }
    __syncthreads();
    if (t < 896) {
      int l = t / 128, d = t % 128;
      x[l][d] = (tmp[l][d] - mu[l]) * inv[l] * ln1w[layer * 128 + d] +
                ln1b[layer * 128 + d];
    }
    __syncthreads();
    gemm7<128, 1, false>(&x[0][0], f1T + layer * 128 * 128, f1b + layer * 128,
                         nullptr, &ybuf[0][0], t);
    __syncthreads();
    gemm7<128, 0, true>(&ybuf[0][0], f2T + layer * 128 * 128, f2b + layer * 128,
                        &x[0][0], &tmp[0][0], t);
    __syncthreads();
    if (t < 448) {
      int row = t >> 6, lane = t & 63;
      float a = tmp[row][lane], c2 = tmp[row][lane + 64];
      float s = a + c2;
      for (int o = 1; o < 64; o <<= 1) s += __shfl_xor(s, o, 64);
      float m = s * (1.0f / 128.0f);
      float d1 = a - m, d2 = c2 - m;
      float v = d1 * d1 + d2 * d2;
      for (int o = 1; o < 64; o <<= 1) v += __shfl_xor(v, o, 64);
      if (lane == 0) { mu[row] = m; inv[row] = 1.0f / sqrtf(v * (1.0f / 128.0f) + 1e-5f); }
    }
    __syncthreads();
    if (t < 896) {
      int l = t / 128, d = t % 128;
      x[l][d] = (tmp[l][d] - mu[l]) * inv[l] * ln2w[layer * 128 + d] +
                ln2b[layer * 128 + d];
    }
    __syncthreads();
  }
  if (t < 64) {
    float s = x[6][t] * fcw[t] + x[6][t + 64] * fcw[t + 64];
    for (int o = 1; o < 64; o <<= 1) s += __shfl_xor(s, o, 64);
    if (t == 0) out[b] = s + fcb[0];
  }
}

extern "C" void kernel_launch(void* const* d_in, const int* in_sizes, int n_in,
                              void* d_out, int out_size, void* d_ws, size_t ws_size,
                              hipStream_t stream) {
  (void)in_sizes; (void)n_in; (void)out_size; (void)ws_size;
  const float* input_img = (const float*)d_in[0];
  const float* cropped = (const float*)d_in[1];
  const float* scale = (const float*)d_in[2];
  const float* conv_w = (const float*)d_in[3];
  const float* fc1_w = (const float*)d_in[4];
  const float* fc1_b = (const float*)d_in[5];
  const float* fc_w = (const float*)d_in[6];
  const float* fc_b = (const float*)d_in[7];
  const float* sa_in_w = (const float*)d_in[8];
  const float* sa_in_b = (const float*)d_in[9];
  const float* sa_out_w = (const float*)d_in[10];
  const float* sa_out_b = (const float*)d_in[11];
  const float* sa_ln1_w = (const float*)d_in[12];
  const float* sa_ln1_b = (const float*)d_in[13];
  const float* sa_fc1_w = (const float*)d_in[14];
  const float* sa_fc1_b = (const float*)d_in[15];
  const float* sa_fc2_w = (const float*)d_in[16];
  const float* sa_fc2_b = (const float*)d_in[17];
  const float* sa_ln2_w = (const float*)d_in[18];
  const float* sa_ln2_b = (const float*)d_in[19];

  char* ws = (char*)d_ws;
  size_t off = 0;
  auto alloc = [&](size_t bytes) -> void* {
    void* p = ws + off;
    off = (off + bytes + 255) & ~(size_t)255;
    return p;
  };
  unsigned short* whi = (unsigned short*)alloc(2048L * 3072 * 2);
  unsigned short* apat = (unsigned short*)alloc(1568L * 3072 * 2);
  unsigned short* winbuf = (unsigned short*)alloc(9408L * 3072 * 2);
  float* emb = (float*)alloc(224L * 2048 * 4);  // 1835008 B (256-aligned)
  float* fm = (float*)alloc(1568L * 4);         // contiguous after emb
  int* tlbuf = (int*)alloc(32L * 6 * 2 * 4);
  float* all_emb = (float*)alloc(32L * 7 * 128 * 4);
  float* fc1T = (float*)alloc(2048L * 128 * 4);
  float* inT = (float*)alloc(3L * 384 * 128 * 4);
  float* outT = (float*)alloc(3L * 128 * 128 * 4);
  float* f1T = (float*)alloc(3L * 128 * 128 * 4);
  float* f2T = (float*)alloc(3L * 128 * 128 * 4);

  // prep: bf16 conversions + patchify + transposes + zero emb/fm (one dispatch)
  prep_kernel<<<6418, 256, 0, stream>>>(conv_w, whi, cropped, apat, fc1_w, fc1T,
                                        sa_in_w, inT, sa_out_w, outT, sa_fc1_w,
                                        f1T, sa_fc2_w, f2T, emb);

  // cropped conv: BM=64 (400 blocks), fused relu+GAP(emb rows 0..31)+fm
  gemm_conv<0, 1><<<dim3(16, 25), 256, 0, stream>>>(apat, whi, emb, fm, 1568);
  coords_kernel<<<32, 64, 0, stream>>>(fm, scale, tlbuf);
  gather_windows<<<14112, 256, 0, stream>>>(input_img, tlbuf, winbuf);
  // windows conv: BM=128 (proven config), fused relu+GAP(emb rows 32..223)
  gemm_conv<1, 2><<<dim3(16, 74), 256, 0, stream>>>(winbuf, whi, emb, nullptr, 9408);
  fc1_kernel<<<224, 512, 0, stream>>>(emb, fc1T, fc1_b, all_emb);
  sa_kernel<<<32, 1024, 0, stream>>>(all_emb, inT, sa_in_b, outT, sa_out_b,
                                     sa_ln1_w, sa_ln1_b, f1T, sa_fc1_b,
                                     f2T, sa_fc2_b, sa_ln2_w, sa_ln2_b,
                                     fc_w, fc_b, (float*)d_out);
}